// Round 3
// baseline (395.139 us; speedup 1.0000x reference)
//
#include <hip/hip_runtime.h>
#include <hip/hip_bf16.h>

#define B_ 64
#define N_ 4096
#define KS 8
#define NCH 16          // token chunks per batch for attention (256 tokens each)
#define TP 136          // padded LDS tile row, bf16 elems
#define LNEPS 1e-5f
#define EPSA 1e-8f
#define SCALE 0.08838834764831845f   // 1/sqrt(128)

typedef short short8  __attribute__((ext_vector_type(8)));
typedef short short4v __attribute__((ext_vector_type(4)));
typedef float f32x4   __attribute__((ext_vector_type(4)));

__device__ __forceinline__ unsigned short f2bf(float f) {
  union { float f; unsigned u; } v; v.f = f;
  unsigned r = v.u + 0x7fffu + ((v.u >> 16) & 1u);   // RNE
  return (unsigned short)(r >> 16);
}
__device__ __forceinline__ float bflo(unsigned u) {
  union { unsigned u; float f; } c; c.u = u << 16; return c.f;
}
__device__ __forceinline__ float bfhi(unsigned u) {
  union { unsigned u; float f; } c; c.u = u & 0xffff0000u; return c.f;
}
__device__ __forceinline__ float sigmf(float x) { return 1.f / (1.f + __expf(-x)); }

// ================= prep_big: fused/transposed weight products =================
// WgT[d*768+j]: j<384 -> (Wih.Wv)[j][d]  (GRU i-side absorbs Wv); else Whh[j-384][d]
// Mq[d*128+t] = SCALE * g_slot[d] * sum_j Wk[j][t]*Wq[j][d]   (qt = Mq^T.LNraw + cq_vec)
// W1gT[d*128+t] = W1[t][d]*g_mlp[d];  W2T[d*128+t] = W2[t][d]
__global__ __launch_bounds__(256) void prep_big(
    const float* __restrict__ Wih, const float* __restrict__ Whh,
    const float* __restrict__ Wq,  const float* __restrict__ Wk,
    const float* __restrict__ Wv,  const float* __restrict__ W1,
    const float* __restrict__ W2,
    const float* __restrict__ g_slot, const float* __restrict__ g_mlp,
    float* __restrict__ WgT, float* __restrict__ Mq,
    float* __restrict__ W1gT, float* __restrict__ W2T)
{
  int id = blockIdx.x * 256 + threadIdx.x;
  if (id < 49152) {                       // Wihv
    int j = id >> 7, d = id & 127;
    float a = 0.f;
    for (int k = 0; k < 128; k++) a += Wih[j*128 + k] * Wv[k*128 + d];
    WgT[d*768 + j] = a;
  } else if (id < 65536) {                // Mq
    int k = id - 49152; int d = k >> 7, t = k & 127;
    float a = 0.f;
    for (int j = 0; j < 128; j++) a += Wk[j*128 + t] * Wq[j*128 + d];
    Mq[d*128 + t] = a * SCALE * g_slot[d];
  } else if (id < 114688) {               // Whh^T into WgT
    int k = id - 65536; int j = k >> 7, d = k & 127;
    WgT[d*768 + 384 + j] = Whh[j*128 + d];
  } else if (id < 131072) {               // W1gT
    int k = id - 114688; int t = k >> 7, d = k & 127;
    W1gT[d*128 + t] = W1[t*128 + d] * g_mlp[d];
  } else if (id < 147456) {               // W2T
    int k = id - 131072; int t = k >> 7, d = k & 127;
    W2T[d*128 + t] = W2[t*128 + d];
  }
}

// ================= prep_small: folded bias vectors (1 block) =================
__global__ __launch_bounds__(256) void prep_small(
    const float* __restrict__ Wq, const float* __restrict__ Wk,
    const float* __restrict__ Wih, const float* __restrict__ W1,
    const float* __restrict__ bq, const float* __restrict__ bk,
    const float* __restrict__ bv, const float* __restrict__ b_ih,
    const float* __restrict__ b_hh, const float* __restrict__ b1,
    const float* __restrict__ b_mlp, const float* __restrict__ b_slot,
    const float* __restrict__ g_slot,
    float* __restrict__ cq_vec, float* __restrict__ wqcg,
    float* __restrict__ qc0g, float* __restrict__ bg, float* __restrict__ b1f)
{
  __shared__ float u[128], wqcr[128];
  int t = threadIdx.x;
  if (t < 128) {                          // u = Wq.b_slot + bq
    float a = bq[t];
    for (int d = 0; d < 128; d++) a += Wq[t*128 + d] * b_slot[d];
    u[t] = a;
  } else {                                // wqcr = SCALE * Wq^T.bk
    int d = t - 128;
    float a = 0.f;
    for (int j = 0; j < 128; j++) a += Wq[j*128 + d] * bk[j];
    wqcr[d] = a * SCALE;
  }
  __syncthreads();
  if (t < 128) {                          // cq_vec = SCALE * Wk^T.u ; wqcg
    float a = 0.f;
    for (int j = 0; j < 128; j++) a += Wk[j*128 + t] * u[j];
    cq_vec[t] = a * SCALE;
    wqcg[t] = wqcr[t] * g_slot[t];
  } else {                                // b1f = b1 + W1.b_mlp
    int d = t - 128;
    float a = b1[d];
    for (int k = 0; k < 128; k++) a += W1[d*128 + k] * b_mlp[k];
    b1f[d] = a;
  }
  if (t < 64) {                           // qc0 = wqcr.b_slot + SCALE*bq.bk
    float v = wqcr[t]*b_slot[t] + wqcr[t+64]*b_slot[t+64]
            + SCALE*(bq[t]*bk[t] + bq[t+64]*bk[t+64]);
    #pragma unroll
    for (int st = 1; st < 64; st <<= 1) v += __shfl_xor(v, st);
    if (t == 0) *qc0g = v;
  }
  #pragma unroll
  for (int p = 0; p < 3; p++) {           // bg: folded GRU bias
    int j = t + p*256;
    if (j < 384) {
      float a = b_ih[j];
      for (int k = 0; k < 128; k++) a += Wih[j*128 + k] * bv[k];
      bg[j] = a;
    } else if (j < 768) {
      bg[j] = b_hh[j - 384];
    }
  }
}

// ================= ln_kernel: xn = bf16(LayerNorm(x)) — pure streaming =================
__global__ __launch_bounds__(256) void ln_kernel(
    const float* __restrict__ x, const float* __restrict__ g_in, const float* __restrict__ b_in,
    unsigned short* __restrict__ xn)
{
  int tid = threadIdx.x;
  int rw = tid >> 2, cp = tid & 3;
  size_t row = (size_t)blockIdx.x * 64 + rw;
  const float* xrow = x + row * 128;
  float4 v[8];
  float s = 0.f, s2 = 0.f;
  #pragma unroll
  for (int i = 0; i < 8; i++) {
    v[i] = *(const float4*)(xrow + (cp + 4*i)*4);
    s  += v[i].x + v[i].y + v[i].z + v[i].w;
    s2 += v[i].x*v[i].x + v[i].y*v[i].y + v[i].z*v[i].z + v[i].w*v[i].w;
  }
  s += __shfl_xor(s, 1); s2 += __shfl_xor(s2, 1);
  s += __shfl_xor(s, 2); s2 += __shfl_xor(s2, 2);
  float mean = s * (1.f/128.f);
  float rstd = rsqrtf(s2 * (1.f/128.f) - mean*mean + LNEPS);
  #pragma unroll
  for (int i = 0; i < 8; i++) {
    int col = (cp + 4*i)*4;
    float4 gg = *(const float4*)(g_in + col);
    float4 bb = *(const float4*)(b_in + col);
    short4v pk;
    pk[0] = (short)f2bf((v[i].x - mean)*rstd*gg.x + bb.x);
    pk[1] = (short)f2bf((v[i].y - mean)*rstd*gg.y + bb.y);
    pk[2] = (short)f2bf((v[i].z - mean)*rstd*gg.z + bb.z);
    pk[3] = (short)f2bf((v[i].w - mean)*rstd*gg.w + bb.w);
    *(short4v*)(xn + row*128 + col) = pk;
  }
}

// ================= q_init: qt/qc from slots_init via precomputed Mq =================
__global__ __launch_bounds__(64) void q_init_kernel(
    const float* __restrict__ slots_in, const float* __restrict__ Mq,
    const float* __restrict__ cq_vec, const float* __restrict__ wqcg,
    const float* __restrict__ qc0g,
    float* __restrict__ qt, float* __restrict__ qc)
{
  __shared__ float lnr[128];
  int row = blockIdx.x, t = threadIdx.x;   // one wave
  float a = slots_in[row*128 + t], b = slots_in[row*128 + 64 + t];
  float s = a + b, s2 = a*a + b*b;
  #pragma unroll
  for (int st = 1; st < 64; st <<= 1) { s += __shfl_xor(s, st); s2 += __shfl_xor(s2, st); }
  float mean = s * (1.f/128.f);
  float rstd = rsqrtf(s2 * (1.f/128.f) - mean*mean + LNEPS);
  lnr[t] = (a - mean)*rstd; lnr[t+64] = (b - mean)*rstd;
  __syncthreads();
  float a0 = cq_vec[t], a1 = cq_vec[t+64];
  for (int d = 0; d < 128; d++) {
    float l = lnr[d];
    a0 += Mq[d*128 + t] * l;
    a1 += Mq[d*128 + 64 + t] * l;
  }
  qt[row*128 + t] = a0; qt[row*128 + 64 + t] = a1;
  float vq = wqcg[t]*lnr[t] + wqcg[t+64]*lnr[t+64];
  #pragma unroll
  for (int st = 1; st < 64; st <<= 1) vq += __shfl_xor(vq, st);
  if (t == 0) qc[row] = vq + *qc0g;
}

// ================= attention sweep with depth-1 register prefetch =================
// grid (NCH=16, B_), 4 waves/block, each wave 4 groups of 16 tokens.
__global__ __launch_bounds__(256) void attn_kernel(
    const unsigned short* __restrict__ xn,
    const float* __restrict__ qt, const float* __restrict__ qc,
    float* __restrict__ Upart, float* __restrict__ Spart)
{
  __shared__ union ShMem {
    unsigned short xt[4][16][TP];   // 17408 B (live during group loop)
    float ured[4][8][128];          // 16384 B (live after final barrier)
  } sh;
  __shared__ __align__(16) float pb[4][16][8];
  __shared__ float sred[4][8];

  const int tid = threadIdx.x;
  const int w = tid >> 6, lane = tid & 63;
  const int chunk = blockIdx.x, batch = blockIdx.y;
  const int m = lane & 15, quad = lane >> 4;

  // A-fragments: q~ rows (slot = m), zeros for m>=8
  short8 afrag[4];
  if (m < KS) {
    const float* qp = qt + (batch*KS + m)*128 + quad*8;
    #pragma unroll
    for (int kc = 0; kc < 4; kc++) {
      short8 a;
      #pragma unroll
      for (int j = 0; j < 8; j++) a[j] = (short)f2bf(qp[kc*32 + j]);
      afrag[kc] = a;
    }
  } else {
    #pragma unroll
    for (int kc = 0; kc < 4; kc++) {
      short8 a;
      #pragma unroll
      for (int j = 0; j < 8; j++) a[j] = 0;
      afrag[kc] = a;
    }
  }
  float creg[4];
  #pragma unroll
  for (int r = 0; r < 4; r++) creg[r] = qc[batch*KS + ((quad*4 + r) & 7)];

  float u0[8], u1[8], sac[4];
  #pragma unroll
  for (int i = 0; i < 8; i++) { u0[i] = 0.f; u1[i] = 0.f; }
  #pragma unroll
  for (int r = 0; r < 4; r++) sac[r] = 0.f;

  const unsigned short* xbase =
      xn + ((size_t)batch*N_ + chunk*256 + w*64 + m)*128 + quad*8;

  short8 cur[4], nxt[4];
  #pragma unroll
  for (int kc = 0; kc < 4; kc++) cur[kc] = *(const short8*)(xbase + kc*32);

  for (int g = 0; g < 4; g++) {
    if (g < 3) {                           // prefetch next group (overlaps compute)
      #pragma unroll
      for (int kc = 0; kc < 4; kc++)
        nxt[kc] = *(const short8*)(xbase + (g+1)*2048 + kc*32);
    }
    // mirror current fragments to LDS (serves the transposed U-pass)
    #pragma unroll
    for (int kc = 0; kc < 4; kc++)
      *(short8*)&sh.xt[w][m][kc*32 + quad*8] = cur[kc];

    f32x4 acc = {0.f, 0.f, 0.f, 0.f};
    #pragma unroll
    for (int kc = 0; kc < 4; kc++)
      acc = __builtin_amdgcn_mfma_f32_16x16x32_bf16(afrag[kc], cur[kc], acc, 0, 0, 0);

    float l[4], o[4];
    #pragma unroll
    for (int r = 0; r < 4; r++) l[r] = acc[r] + creg[r];
    #pragma unroll
    for (int r = 0; r < 4; r++) o[r] = __shfl_xor(l[r], 16);   // swap slot halves
    float mx = fmaxf(fmaxf(fmaxf(l[0], l[1]), fmaxf(l[2], l[3])),
                     fmaxf(fmaxf(o[0], o[1]), fmaxf(o[2], o[3])));
    float e0 = __expf(l[0]-mx), e1 = __expf(l[1]-mx), e2 = __expf(l[2]-mx), e3 = __expf(l[3]-mx);
    float den = e0+e1+e2+e3 + __expf(o[0]-mx)+__expf(o[1]-mx)+__expf(o[2]-mx)+__expf(o[3]-mx);
    float rd = 1.f / den;
    float p0 = e0*rd + EPSA, p1 = e1*rd + EPSA, p2 = e2*rd + EPSA, p3 = e3*rd + EPSA;
    sac[0] += p0; sac[1] += p1; sac[2] += p2; sac[3] += p3;
    if (lane < 32) {
      float4 pv; pv.x = p0; pv.y = p1; pv.z = p2; pv.w = p3;
      *(float4*)&pb[w][m][quad*4] = pv;
    }

    // U~ accumulate: lane owns dims 2*lane, 2*lane+1
    #pragma unroll
    for (int t = 0; t < 16; t++) {
      float4 pA = *(const float4*)&pb[w][t][0];
      float4 pB = *(const float4*)&pb[w][t][4];
      unsigned vp = *(const unsigned*)&sh.xt[w][t][lane*2];
      float f0 = bflo(vp), f1 = bfhi(vp);
      u0[0] += pA.x*f0; u1[0] += pA.x*f1;
      u0[1] += pA.y*f0; u1[1] += pA.y*f1;
      u0[2] += pA.z*f0; u1[2] += pA.z*f1;
      u0[3] += pA.w*f0; u1[3] += pA.w*f1;
      u0[4] += pB.x*f0; u1[4] += pB.x*f1;
      u0[5] += pB.y*f0; u1[5] += pB.y*f1;
      u0[6] += pB.z*f0; u1[6] += pB.z*f1;
      u0[7] += pB.w*f0; u1[7] += pB.w*f1;
    }
    #pragma unroll
    for (int kc = 0; kc < 4; kc++) cur[kc] = nxt[kc];
  }

  // S: reduce over the 16 token-lanes per quad-pair
  #pragma unroll
  for (int st = 1; st < 16; st <<= 1) {
    #pragma unroll
    for (int r = 0; r < 4; r++) sac[r] += __shfl_xor(sac[r], st);
  }
  if (lane == 0)  { sred[w][0]=sac[0]; sred[w][1]=sac[1]; sred[w][2]=sac[2]; sred[w][3]=sac[3]; }
  if (lane == 16) { sred[w][4]=sac[0]; sred[w][5]=sac[1]; sred[w][6]=sac[2]; sred[w][7]=sac[3]; }

  __syncthreads();                       // xt dead -> reuse as ured
  #pragma unroll
  for (int i = 0; i < 8; i++)
    *(float2*)&sh.ured[w][i][lane*2] = make_float2(u0[i], u1[i]);
  __syncthreads();

  {
    const float* ur = &sh.ured[0][0][0];
    int i4 = tid * 4;
    float4 a = *(const float4*)(ur + i4);
    float4 b = *(const float4*)(ur + 1024 + i4);
    float4 c = *(const float4*)(ur + 2048 + i4);
    float4 d = *(const float4*)(ur + 3072 + i4);
    float4 o4;
    o4.x = a.x+b.x+c.x+d.x; o4.y = a.y+b.y+c.y+d.y;
    o4.z = a.z+b.z+c.z+d.z; o4.w = a.w+b.w+c.w+d.w;
    *(float4*)(Upart + (size_t)(batch*NCH + chunk)*1024 + i4) = o4;
    if (tid < 8)
      Spart[(batch*NCH + chunk)*8 + tid] =
        sred[0][tid] + sred[1][tid] + sred[2][tid] + sred[3][tid];
  }
}

// ================= per-slot-row update (shortened chain) =================
__global__ __launch_bounds__(256) void update_kernel(
    const float* __restrict__ slots_in, float* __restrict__ slots_out,
    const float* __restrict__ Upart, const float* __restrict__ Spart,
    const float* __restrict__ WgT, const float* __restrict__ bg,
    const float* __restrict__ W1gT, const float* __restrict__ b1f,
    const float* __restrict__ W2T, const float* __restrict__ b2,
    const float* __restrict__ Mq, const float* __restrict__ cq_vec,
    const float* __restrict__ wqcg, const float* __restrict__ qc0g,
    float* __restrict__ qt, float* __restrict__ qc)
{
  __shared__ float bu[128], hb[128], gg[768];
  __shared__ float s1[128], lnr[128], hmv[128], s2v[128], lnr2[128];
  __shared__ float stats[2], sSum;
  int row = blockIdx.x, t = threadIdx.x;
  int batch = row >> 3, slot = row & 7;

  float usum = 0.f;
  if (t < 128) {                          // Upart reduce (16 chunks)
    const float* Up = Upart + ((size_t)(batch*NCH)*8 + slot)*128 + t;
    #pragma unroll
    for (int c = 0; c < NCH; c++) usum += Up[(size_t)c*1024];
  } else {
    hb[t-128] = slots_in[row*128 + (t-128)];
    if (t < 192) {                        // wave 2: Spart reduce
      int l2 = t - 128;
      float sv = (l2 < NCH) ? Spart[(batch*NCH + l2)*8 + slot] : 0.f;
      #pragma unroll
      for (int st = 1; st < 16; st <<= 1) sv += __shfl_xor(sv, st);
      if (l2 == 0) sSum = sv;
    }
  }
  __syncthreads();
  if (t < 128) bu[t] = usum / sSum;
  __syncthreads();
  {  // GRU gemv over combined WgT[128][768] (i-side absorbs Wv)
    float a0 = bg[t], a1 = bg[t+256], a2 = bg[t+512];
    const float* v1p = (t < 128) ? bu : hb;
    for (int d = 0; d < 128; d++) {
      float sd = bu[d], hd = hb[d], vd = v1p[d];
      const float* wr = WgT + d*768 + t;
      a0 += sd * wr[0];
      a1 += vd * wr[256];
      a2 += hd * wr[512];
    }
    gg[t] = a0; gg[t+256] = a1; gg[t+512] = a2;
  }
  __syncthreads();
  if (t < 128) {                          // GRU gates
    float r = sigmf(gg[t] + gg[384+t]);
    float z = sigmf(gg[128+t] + gg[512+t]);
    float n = tanhf(gg[256+t] + r * gg[640+t]);
    s1[t] = (1.f - z)*n + z*hb[t];
  }
  __syncthreads();
  if (t < 64) {
    float a = s1[t], b = s1[t+64];
    float s = a + b, s2 = a*a + b*b;
    #pragma unroll
    for (int st = 1; st < 64; st <<= 1) { s += __shfl_xor(s, st); s2 += __shfl_xor(s2, st); }
    if (t == 0) { float mean = s*(1.f/128.f); stats[0] = mean;
                  stats[1] = rsqrtf(s2*(1.f/128.f) - mean*mean + LNEPS); }
  }
  __syncthreads();
  if (t < 128) lnr[t] = (s1[t] - stats[0])*stats[1];
  __syncthreads();
  if (t < 128) {                          // W1g gemv + relu (g_mlp folded)
    float a = b1f[t];
    for (int d = 0; d < 128; d++) a += W1gT[d*128 + t]*lnr[d];
    hmv[t] = fmaxf(a, 0.f);
  }
  __syncthreads();
  if (t < 128) {                          // W2 gemv + residual
    float a = s1[t] + b2[t];
    for (int d = 0; d < 128; d++) a += W2T[d*128 + t]*hmv[d];
    s2v[t] = a;
    slots_out[row*128 + t] = a;
  }
  __syncthreads();
  if (t < 64) {
    float a = s2v[t], b = s2v[t+64];
    float s = a + b, s2 = a*a + b*b;
    #pragma unroll
    for (int st = 1; st < 64; st <<= 1) { s += __shfl_xor(s, st); s2 += __shfl_xor(s2, st); }
    if (t == 0) { float mean = s*(1.f/128.f); stats[0] = mean;
                  stats[1] = rsqrtf(s2*(1.f/128.f) - mean*mean + LNEPS); }
  }
  __syncthreads();
  if (t < 128) lnr2[t] = (s2v[t] - stats[0])*stats[1];
  __syncthreads();
  if (t < 128) {                          // qt = Mq^T.lnr2 + cq_vec (g_slot,Wq,Wk folded)
    float a = cq_vec[t];
    for (int d = 0; d < 128; d++) a += Mq[d*128 + t]*lnr2[d];
    qt[row*128 + t] = a;
  }
  if (t < 64) {
    float v = wqcg[t]*lnr2[t] + wqcg[t+64]*lnr2[t+64];
    #pragma unroll
    for (int st = 1; st < 64; st <<= 1) v += __shfl_xor(v, st);
    if (t == 0) qc[row] = v + *qc0g;
  }
}

extern "C" void kernel_launch(void* const* d_in, const int* in_sizes, int n_in,
                              void* d_out, int out_size, void* d_ws, size_t ws_size,
                              hipStream_t stream) {
  const float* x          = (const float*)d_in[0];
  const float* slots_init = (const float*)d_in[1];
  const float* Wq   = (const float*)d_in[2];
  const float* bq   = (const float*)d_in[3];
  const float* Wk   = (const float*)d_in[4];
  const float* bk   = (const float*)d_in[5];
  const float* Wv   = (const float*)d_in[6];
  const float* bv   = (const float*)d_in[7];
  const float* g_in = (const float*)d_in[8];
  const float* b_in = (const float*)d_in[9];
  const float* g_slot = (const float*)d_in[10];
  const float* b_slot = (const float*)d_in[11];
  const float* g_mlp  = (const float*)d_in[12];
  const float* b_mlp  = (const float*)d_in[13];
  const float* W1   = (const float*)d_in[14];
  const float* b1   = (const float*)d_in[15];
  const float* W2   = (const float*)d_in[16];
  const float* b2   = (const float*)d_in[17];
  const float* Wih  = (const float*)d_in[18];
  const float* Whh  = (const float*)d_in[19];
  const float* b_ih = (const float*)d_in[20];
  const float* b_hh = (const float*)d_in[21];

  char* p = (char*)d_ws;
  unsigned short* xn = (unsigned short*)p; p += (size_t)B_*N_*128*2;   // 64 MB
  float* qt    = (float*)p; p += (size_t)B_*KS*128*4;
  float* qc    = (float*)p; p += (size_t)B_*KS*4 + 1024;
  float* slots = (float*)p; p += (size_t)B_*KS*128*4;
  float* Upart = (float*)p; p += (size_t)B_*NCH*KS*128*4;              // 4 MB
  float* Spart = (float*)p; p += (size_t)B_*NCH*KS*4 + 1024;
  float* WgT   = (float*)p; p += 98304*4;
  float* Mq    = (float*)p; p += 16384*4;
  float* W1gT  = (float*)p; p += 16384*4;
  float* W2T   = (float*)p; p += 16384*4;
  float* cq_vec= (float*)p; p += 128*4;
  float* wqcg  = (float*)p; p += 128*4;
  float* qc0g  = (float*)p; p += 256;
  float* bg    = (float*)p; p += 768*4;
  float* b1f   = (float*)p; p += 128*4;

  ln_kernel<<<4096, 256, 0, stream>>>(x, g_in, b_in, xn);
  prep_big<<<576, 256, 0, stream>>>(Wih, Whh, Wq, Wk, Wv, W1, W2, g_slot, g_mlp,
                                    WgT, Mq, W1gT, W2T);
  prep_small<<<1, 256, 0, stream>>>(Wq, Wk, Wih, W1, bq, bk, bv, b_ih, b_hh, b1,
                                    b_mlp, b_slot, g_slot, cq_vec, wqcg, qc0g, bg, b1f);
  q_init_kernel<<<512, 64, 0, stream>>>(slots_init, Mq, cq_vec, wqcg, qc0g, qt, qc);

  attn_kernel<<<dim3(NCH, B_), 256, 0, stream>>>(xn, qt, qc, Upart, Spart);
  update_kernel<<<512, 256, 0, stream>>>(slots_init, slots, Upart, Spart,
      WgT, bg, W1gT, b1f, W2T, b2, Mq, cq_vec, wqcg, qc0g, qt, qc);

  attn_kernel<<<dim3(NCH, B_), 256, 0, stream>>>(xn, qt, qc, Upart, Spart);
  update_kernel<<<512, 256, 0, stream>>>(slots, slots, Upart, Spart,
      WgT, bg, W1gT, b1f, W2T, b2, Mq, cq_vec, wqcg, qc0g, qt, qc);

  attn_kernel<<<dim3(NCH, B_), 256, 0, stream>>>(xn, qt, qc, Upart, Spart);
  update_kernel<<<512, 256, 0, stream>>>(slots, (float*)d_out, Upart, Spart,
      WgT, bg, W1gT, b1f, W2T, b2, Mq, cq_vec, wqcg, qc0g, qt, qc);

  (void)in_sizes; (void)n_in; (void)out_size; (void)ws_size;
}